// Round 9
// baseline (201.247 us; speedup 1.0000x reference)
//
#include <hip/hip_runtime.h>

// MultiHeadAttention: B=2, N=2048, C=768, H=12, DH=64. fp32 in/out, bf16 MFMA compute.
// R14 = R13 + GEMM grid de-starvation (inner structure unchanged = R5 proven):
//  - gemm_qkv: 128(M)x64(N) tiles -> 1152 blocks (4.5/CU, was 2.25); wave=64x32,
//    acc[4][2].
//  - gemm_proj: 64x64 tiles -> 768 blocks (3.0/CU perfectly balanced, was 0.75!);
//    wave=32x32, acc[2][2].
//  Same BK=64, same staging pattern, same MFMA accumulation order -> numerics
//  bit-identical.  attn (56us, best) and cvt_all unchanged from R13.

typedef __bf16 bf16_t;
typedef __bf16 bf16x8 __attribute__((ext_vector_type(8)));
typedef __bf16 bf16x4 __attribute__((ext_vector_type(4)));
typedef short  short4_t __attribute__((ext_vector_type(4)));
typedef float  floatx4 __attribute__((ext_vector_type(4)));

#define MFMA32(a, b, c) __builtin_amdgcn_mfma_f32_16x16x32_bf16(a, b, c, 0, 0, 0)
#define MFMA16(a, b, c) __builtin_amdgcn_mfma_f32_16x16x16bf16_1k(a, b, c, 0, 0, 0)

__device__ __forceinline__ void gload16(const bf16_t* g, bf16_t* l) {
  __builtin_amdgcn_global_load_lds(
      (__attribute__((address_space(1))) void*)g,
      (__attribute__((address_space(3))) void*)l, 16, 0, 0);
}

// ---------------------------------------------------------------- converts --
// One kernel, 1D grid 3648: blocks [0,3072) convert x fp32->bf16 (vectorized);
// blocks [3072,3648) transpose+convert the 4 weight matrices (64x64 LDS tiles).
__global__ __launch_bounds__(256) void cvt_all_kernel(
    const float* __restrict__ x, const float* __restrict__ W0,
    const float* __restrict__ W1, const float* __restrict__ W2,
    const float* __restrict__ W3, bf16_t* __restrict__ xb,
    bf16_t* __restrict__ T0, bf16_t* __restrict__ T1,
    bf16_t* __restrict__ T2, bf16_t* __restrict__ T3) {
  __shared__ bf16_t T[64][65];
  const int id = blockIdx.x;
  if (id < 3072) {
    int i = id * 256 + threadIdx.x;
    floatx4 v = ((const floatx4*)x)[i];
    bf16x4 o;
    o[0] = (bf16_t)v[0]; o[1] = (bf16_t)v[1]; o[2] = (bf16_t)v[2]; o[3] = (bf16_t)v[3];
    ((bf16x4*)xb)[i] = o;
    return;
  }
  const int wid = id - 3072;              // 0..575
  const int z = wid / 144, rem = wid % 144;
  const int by = rem / 12, bx = rem % 12;
  const float* W = (z == 0) ? W0 : (z == 1) ? W1 : (z == 2) ? W2 : W3;
  bf16_t* WT = (z == 0) ? T0 : (z == 1) ? T1 : (z == 2) ? T2 : T3;
  const int c = threadIdx.x & 63, r0 = threadIdx.x >> 6;
  const int i0 = by * 64, o0 = bx * 64;
#pragma unroll
  for (int p = 0; p < 16; ++p) {
    int r = p * 4 + r0;
    T[r][c] = (bf16_t)W[(i0 + r) * 768 + o0 + c];
  }
  __syncthreads();
#pragma unroll
  for (int p = 0; p < 16; ++p) {
    int r = p * 4 + r0;
    WT[(o0 + r) * 768 + i0 + c] = T[c][r];
  }
}

// ------------------------------------------------------------------- GEMMs --
#define LDPG 72  // BK=64 + 8 pad

// Fragment-order layouts (per bh = b*12+h, per 128-key tile kt):
//  K: elem(key,d) -> kt*8192 + ((nk*2+kk)*64 + quad*16 + l15)*8 + j
//     nk=key128>>4, l15=key128&15, kk=d>>5, quad=(d>>3)&3, j=d&7
//  V: elem(key,d) -> kt*8192 + ((nk*4+nd)*64 + vq*16 + vl15)*4 + j
//     nk=key128>>4, vq=(key128>>2)&3, j=key128&3, nd=d>>4, vl15=d&15

// Fused QKV: M=768 channels (tile 128), N=4096 tokens (tile 64).
// Grid (64, 6, 3) = 1152 blocks = 4.5/CU.  Wave (2Mx2N): 64 M x 32 N, acc[4][2].
__global__ __launch_bounds__(256) void gemm_qkv(
    const bf16_t* __restrict__ Xb, const bf16_t* __restrict__ WqT,
    const bf16_t* __restrict__ WkT, const bf16_t* __restrict__ WvT,
    const float* __restrict__ bq, const float* __restrict__ bk,
    const float* __restrict__ bv, bf16_t* __restrict__ qw,
    bf16_t* __restrict__ kw, bf16_t* __restrict__ vtw) {
  __shared__ bf16_t Al[128 * LDPG];
  __shared__ bf16_t Bl[64 * LDPG];
  const int z = blockIdx.z;
  const bf16_t* Wt = (z == 0) ? WqT : (z == 1) ? WkT : WvT;
  const float* bias = (z == 0) ? bq : (z == 1) ? bk : bv;
  const float oscale = (z == 0) ? 0.18033688011112042f : 1.0f;  // 0.125*log2(e)

  const int tid = threadIdx.x, lane = tid & 63, w = tid >> 6;
  const int wr = w >> 1, wc = w & 1;
  const int l15 = lane & 15, quad = lane >> 4;
  const int m0 = blockIdx.y * 128, n0 = blockIdx.x * 64;

  floatx4 acc[4][2] = {};

  for (int kt = 0; kt < 768; kt += 64) {
#pragma unroll
    for (int p = 0; p < 4; ++p) {        // A: 128 rows
      int c = p * 256 + tid;
      int row = c >> 3, qo = (c & 7) * 8;
      *(bf16x8*)&Al[row * LDPG + qo] = *(const bf16x8*)&Wt[(m0 + row) * 768 + kt + qo];
    }
#pragma unroll
    for (int p = 0; p < 2; ++p) {        // B: 64 rows
      int c = p * 256 + tid;
      int row = c >> 3, qo = (c & 7) * 8;
      *(bf16x8*)&Bl[row * LDPG + qo] = *(const bf16x8*)&Xb[(n0 + row) * 768 + kt + qo];
    }
    __syncthreads();
#pragma unroll
    for (int kk = 0; kk < 2; ++kk) {
      bf16x8 af[4], bfr[2];
#pragma unroll
      for (int i = 0; i < 4; ++i)
        af[i]  = *(bf16x8*)&Al[(wr * 64 + i * 16 + l15) * LDPG + kk * 32 + quad * 8];
#pragma unroll
      for (int i = 0; i < 2; ++i)
        bfr[i] = *(bf16x8*)&Bl[(wc * 32 + i * 16 + l15) * LDPG + kk * 32 + quad * 8];
#pragma unroll
      for (int mi = 0; mi < 4; ++mi)
#pragma unroll
        for (int ni = 0; ni < 2; ++ni)
          acc[mi][ni] = MFMA32(af[mi], bfr[ni], acc[mi][ni]);
    }
    __syncthreads();
  }

  const int hh = (m0 + wr * 64) >> 6;  // head (64-aligned per wave-row)
#pragma unroll
  for (int mi = 0; mi < 4; ++mi) {
    const int d0 = mi * 16 + quad * 4;           // d within head, multiple of 4
    const int gm0 = m0 + wr * 64 + d0;
    float bv4[4];
#pragma unroll
    for (int r = 0; r < 4; ++r) bv4[r] = bias[gm0 + r];
#pragma unroll
    for (int ni = 0; ni < 2; ++ni) {
      const int gn = n0 + wc * 32 + ni * 16 + l15;
      const int bb = gn >> 11, tok = gn & 2047;
      const int bh = bb * 12 + hh;
      if (z == 0) {
        bf16x4 pk;
#pragma unroll
        for (int r = 0; r < 4; ++r)
          pk[r] = (bf16_t)((acc[mi][ni][r] + bv4[r]) * oscale);
        *(bf16x4*)&qw[bh * 131072 + tok * 64 + d0] = pk;
      } else if (z == 1) {
        const int kt2 = tok >> 7, k128 = tok & 127;
        const int nk = k128 >> 4, kl15 = k128 & 15;
        const int kk = d0 >> 5, kq = (d0 >> 3) & 3, j0 = d0 & 7;
        bf16x4 pk;
#pragma unroll
        for (int r = 0; r < 4; ++r)
          pk[r] = (bf16_t)(acc[mi][ni][r] + bv4[r]);
        *(bf16x4*)&kw[bh * 131072 + kt2 * 8192 +
                      ((nk * 2 + kk) * 64 + kq * 16 + kl15) * 8 + j0] = pk;
      } else {
        const int kt2 = tok >> 7, k128 = tok & 127;
        const int nk = k128 >> 4, vq = (k128 >> 2) & 3, j = k128 & 3;
        const int nd = d0 >> 4, vl0 = d0 & 15;
        const int base = bh * 131072 + kt2 * 8192 +
                         ((nk * 4 + nd) * 64 + vq * 16 + vl0) * 4 + j;
#pragma unroll
        for (int r = 0; r < 4; ++r)
          vtw[base + r * 4] = (bf16_t)(acc[mi][ni][r] + bv4[r]);
      }
    }
  }
}

// Output projection: M=768 channels (tile 64), N=4096 tokens (tile 64).
// Grid (64, 12) = 768 blocks = 3.0/CU balanced.  Wave (2x2): 32x32, acc[2][2].
__global__ __launch_bounds__(256) void gemm_proj(
    const bf16_t* __restrict__ Yb, const bf16_t* __restrict__ WpT,
    const float* __restrict__ bias, float* __restrict__ out) {
  __shared__ bf16_t Al[64 * LDPG];
  __shared__ bf16_t Bl[64 * LDPG];
  const int tid = threadIdx.x, lane = tid & 63, w = tid >> 6;
  const int wr = w >> 1, wc = w & 1;
  const int l15 = lane & 15, quad = lane >> 4;
  const int m0 = blockIdx.y * 64, n0 = blockIdx.x * 64;

  floatx4 acc[2][2] = {};

  for (int kt = 0; kt < 768; kt += 64) {
#pragma unroll
    for (int p = 0; p < 2; ++p) {
      int c = p * 256 + tid;
      int row = c >> 3, qo = (c & 7) * 8;
      *(bf16x8*)&Al[row * LDPG + qo] = *(const bf16x8*)&WpT[(m0 + row) * 768 + kt + qo];
      *(bf16x8*)&Bl[row * LDPG + qo] = *(const bf16x8*)&Yb[(n0 + row) * 768 + kt + qo];
    }
    __syncthreads();
#pragma unroll
    for (int kk = 0; kk < 2; ++kk) {
      bf16x8 af[2], bfr[2];
#pragma unroll
      for (int i = 0; i < 2; ++i) {
        af[i]  = *(bf16x8*)&Al[(wr * 32 + i * 16 + l15) * LDPG + kk * 32 + quad * 8];
        bfr[i] = *(bf16x8*)&Bl[(wc * 32 + i * 16 + l15) * LDPG + kk * 32 + quad * 8];
      }
#pragma unroll
      for (int mi = 0; mi < 2; ++mi)
#pragma unroll
        for (int ni = 0; ni < 2; ++ni)
          acc[mi][ni] = MFMA32(af[mi], bfr[ni], acc[mi][ni]);
    }
    __syncthreads();
  }

#pragma unroll
  for (int mi = 0; mi < 2; ++mi) {
    const int gm0 = m0 + wr * 32 + mi * 16 + quad * 4;
    floatx4 bv4;
#pragma unroll
    for (int r = 0; r < 4; ++r) bv4[r] = bias[gm0 + r];
#pragma unroll
    for (int ni = 0; ni < 2; ++ni) {
      const int gn = n0 + wc * 32 + ni * 16 + l15;
      floatx4 v = acc[mi][ni] + bv4;
      *(floatx4*)&out[gn * 768 + gm0] = v;
    }
  }
}

// --------------------------------------------------------------- attention --
// Block: one (b,h), 64 Q rows.  Wave w=(wk<<1)|wq: wq picks 32-q half, wk picks
// the 32-key half of each 64-key tile.  K/V in fragment order -> each 64-key
// subtile is a contiguous 8KB range; staging = linear global_load_lds copy
// (no VGPRs, no VALU).  Double-buffered: stage(next) overlaps compute(cur);
// one __syncthreads per tile (its vmcnt(0) drain hits loads issued a full
// compute-phase earlier).  XCD mapping: block i -> XCD i&7; XCD x owns bh in
// [3x,3x+3) (1.5MB K/V, L2-resident).  lsum on MFMA pipe (ones-trick).
__global__ __launch_bounds__(256, 4) void attn_kernel(
    const bf16_t* __restrict__ Q, const bf16_t* __restrict__ Kf,
    const bf16_t* __restrict__ Vf, bf16_t* __restrict__ Y) {
  // buf b at smem+b*8192: K [0,4096), V [4096,8192) (elements)
  __shared__ __align__(16) bf16_t smem[16384];
  __shared__ float Ls[2][2][2][16];             // [wq][wk][ni][q&15]
  float* Ox = (float*)smem;                     // exchange region (16 KB used)

  const int tid = threadIdx.x, lane = tid & 63, w = tid >> 6;
  const int wq = w & 1, wk = w >> 1;
  const int l15 = lane & 15, quad = lane >> 4;

  // XCD-aware mapping (perf-only heuristic; any mapping is correct).
  const int i = blockIdx.x;           // 0..767
  const int xcd = i & 7, j = i >> 3;  // j: 0..95
  const int bh = xcd * 3 + (j >> 5);
  const int q0 = (j & 31) * 64;

  const bf16_t* Qb = Q + bh * 131072;
  const bf16_t* Kg = Kf + bh * 131072 + tid * 8;  // per-thread staging base
  const bf16_t* Vg = Vf + bh * 131072 + tid * 8;

  // Q B-frags (x32): n=q over l15, k=dh over quad*8+j.  32 q per wave.
  bf16x8 qf[2][2];
#pragma unroll
  for (int ni = 0; ni < 2; ++ni)
#pragma unroll
    for (int kk = 0; kk < 2; ++kk)
      qf[ni][kk] = *(const bf16x8*)&Qb[(q0 + wq * 32 + ni * 16 + l15) * 64 +
                                       kk * 32 + quad * 8];

  floatx4 oacc[2][4] = {};   // [ni(q16)][nd(d16)] partial over this wave's keys
  floatx4 sacc[2] = {};      // row-sums via MFMA ones-trick
  const short4_t ones = {0x3F80, 0x3F80, 0x3F80, 0x3F80};  // bf16 1.0 x4

  // stage 64-key tile t (elements [t*4096, t*4096+4096) of K and of V) into buf b
  auto stage = [&](int b, int t) {
    const bf16_t* kg = Kg + t * 4096;
    const bf16_t* vg = Vg + t * 4096;
    bf16_t* kl = smem + b * 8192 + tid * 8;
    bf16_t* vl = smem + b * 8192 + 4096 + tid * 8;
    gload16(kg, kl);
    gload16(kg + 2048, kl + 2048);
    gload16(vg, vl);
    gload16(vg + 2048, vl + 2048);
  };

  auto compute = [&](int b) {
    const bf16_t* Kl = smem + b * 8192;
    const bf16_t* Vl = smem + b * 8192 + 4096;
    // S^T = K*Q^T for this wave's 32 keys x 32 q; P = exp2 packed to x16 A-frags.
    short4_t pk[2][2];
#pragma unroll
    for (int mt = 0; mt < 2; ++mt) {
      floatx4 s[2] = {};
#pragma unroll
      for (int kk = 0; kk < 2; ++kk) {
        bf16x8 kfr = *(const bf16x8*)&Kl[((wk * 2 + mt) * 2 + kk) * 512 + lane * 8];
#pragma unroll
        for (int ni = 0; ni < 2; ++ni)
          s[ni] = MFMA32(kfr, qf[ni][kk], s[ni]);
      }
#pragma unroll
      for (int ni = 0; ni < 2; ++ni) {
        bf16x4 ph;
#pragma unroll
        for (int r = 0; r < 4; ++r)
          ph[r] = (bf16_t)__builtin_amdgcn_exp2f(s[ni][r]);
        pk[mt][ni] = __builtin_bit_cast(short4_t, ph);
      }
    }
    // O += P*V; sacc += P*1 (row-sums on the MFMA pipe).
#pragma unroll
    for (int mt = 0; mt < 2; ++mt) {
#pragma unroll
      for (int nd = 0; nd < 4; ++nd) {
        bf16x4 vfr = *(const bf16x4*)&Vl[((wk * 2 + mt) * 4 + nd) * 256 + lane * 4];
        short4_t vs = __builtin_bit_cast(short4_t, vfr);
#pragma unroll
        for (int ni = 0; ni < 2; ++ni)
          oacc[ni][nd] = MFMA16(pk[mt][ni], vs, oacc[ni][nd]);
      }
#pragma unroll
      for (int ni = 0; ni < 2; ++ni)
        sacc[ni] = MFMA16(pk[mt][ni], ones, sacc[ni]);
    }
  };

  stage(0, 0);
  __syncthreads();                       // buf0 ready (vmcnt(0) drain + barrier)
  for (int t = 0; t < 32; t += 2) {
    stage(1, t + 1);                     // async into buf1 during compute(buf0)
    compute(0);
    __syncthreads();                     // buf1 ready; everyone done with buf0
    if (t + 2 < 32) stage(0, t + 2);     // async into buf0 during compute(buf1)
    compute(1);
    __syncthreads();                     // buf0 ready; everyone done with buf1
  }

  // sacc[ni][r] = this wave's lsum for q = ni*16 + quad*4 + r (same across l15).
  if (l15 == 0) {
#pragma unroll
    for (int ni = 0; ni < 2; ++ni)
#pragma unroll
      for (int r = 0; r < 4; ++r)
        Ls[wq][wk][ni][quad * 4 + r] = sacc[ni][r];
  }

  // Each wave writes its NON-owned d-half (fp32, b128, conflict-free),
  // then reads partner's partial for its owned half.
#pragma unroll
  for (int ni = 0; ni < 2; ++ni)
#pragma unroll
    for (int ndl = 0; ndl < 2; ++ndl) {
      const int nd = (1 - wk) * 2 + ndl;
      *(floatx4*)&Ox[((((wq * 2 + wk) * 2 + ni) * 2 + ndl) * 64 + lane) * 4] =
          oacc[ni][nd];
    }
  __syncthreads();

  const int bb = bh / 12, h = bh % 12;
#pragma unroll
  for (int ni = 0; ni < 2; ++ni) {
    float tot[4];
#pragma unroll
    for (int r = 0; r < 4; ++r)
      tot[r] = Ls[wq][0][ni][quad * 4 + r] + Ls[wq][1][ni][quad * 4 + r];
#pragma unroll
    for (int ndl = 0; ndl < 2; ++ndl) {
      const int nd = wk * 2 + ndl;
      floatx4 o = oacc[ni][nd];
      floatx4 other =
          *(floatx4*)&Ox[((((wq * 2 + (1 - wk)) * 2 + ni) * 2 + ndl) * 64 + lane) * 4];
      o += other;
#pragma unroll
      for (int r = 0; r < 4; ++r) {
        const int tok = q0 + wq * 32 + ni * 16 + quad * 4 + r;
        const int col = h * 64 + nd * 16 + l15;
        Y[(bb * 2048 + tok) * 768 + col] = (bf16_t)(o[r] / tot[r]);
      }
    }
  }
}

// ------------------------------------------------------------------ launch --
extern "C" void kernel_launch(void* const* d_in, const int* in_sizes, int n_in,
                              void* d_out, int out_size, void* d_ws, size_t ws_size,
                              hipStream_t stream) {
  const float* x  = (const float*)d_in[0];
  const float* Wq = (const float*)d_in[1];
  const float* bq = (const float*)d_in[2];
  const float* Wk = (const float*)d_in[3];
  const float* bk = (const float*)d_in[4];
  const float* Wv = (const float*)d_in[5];
  const float* bv = (const float*)d_in[6];
  const float* Wp = (const float*)d_in[7];
  const float* bp = (const float*)d_in[8];
  float* out = (float*)d_out;

  char* ws = (char*)d_ws;
  bf16_t* xb  = (bf16_t*)ws; ws += (size_t)4096 * 768 * 2;
  bf16_t* WqT = (bf16_t*)ws; ws += (size_t)768 * 768 * 2;
  bf16_t* WkT = (bf16_t*)ws; ws += (size_t)768 * 768 * 2;
  bf16_t* WvT = (bf16_t*)ws; ws += (size_t)768 * 768 * 2;
  bf16_t* WpT = (bf16_t*)ws; ws += (size_t)768 * 768 * 2;
  bf16_t* qw  = (bf16_t*)ws; ws += (size_t)24 * 2048 * 64 * 2;
  bf16_t* kw  = (bf16_t*)ws; ws += (size_t)24 * 2048 * 64 * 2;
  bf16_t* vtw = (bf16_t*)ws; ws += (size_t)24 * 2048 * 64 * 2;
  bf16_t* yw  = (bf16_t*)ws; ws += (size_t)4096 * 768 * 2;

  cvt_all_kernel<<<3648, 256, 0, stream>>>(x, Wq, Wk, Wv, Wp, xb, WqT, WkT, WvT, WpT);
  gemm_qkv<<<dim3(64, 6, 3), 256, 0, stream>>>(xb, WqT, WkT, WvT, bq, bk, bv, qw, kw, vtw);
  attn_kernel<<<768, 256, 0, stream>>>(qw, kw, vtw, yw);
  gemm_proj<<<dim3(64, 12), 256, 0, stream>>>(yw, WpT, bp, out);
}

// Round 10
// 177.669 us; speedup vs baseline: 1.1327x; 1.1327x over previous
//
#include <hip/hip_runtime.h>

// MultiHeadAttention: B=2, N=2048, C=768, H=12, DH=64. fp32 in/out, bf16 MFMA compute.
// R15 = R13 (best, 186.3us) + GEMM staging MLP restoration:
//  - __launch_bounds__(256,2): VGPR budget 256 so the allocator stops
//    serializing staging loads to hit 8 waves/SIMD (all GEMM variants so far
//    compiled to 56-64 VGPR -> ~no memory-level parallelism in the stage phase;
//    R14's direct counters: MfmaUtil 8.8% at 24% occupancy = latency-bound).
//  - explicit two-phase staging: 8 NAMED bf16x8 loads (all in flight), then
//    8 ds_writes.  Same rows/cols/order as R13 -> bit-identical numerics.
// Tiles/grids = R13 (128x128, qkv (32,6,3), proj (32,6)).  attn/cvt unchanged.

typedef __bf16 bf16_t;
typedef __bf16 bf16x8 __attribute__((ext_vector_type(8)));
typedef __bf16 bf16x4 __attribute__((ext_vector_type(4)));
typedef short  short4_t __attribute__((ext_vector_type(4)));
typedef float  floatx4 __attribute__((ext_vector_type(4)));

#define MFMA32(a, b, c) __builtin_amdgcn_mfma_f32_16x16x32_bf16(a, b, c, 0, 0, 0)
#define MFMA16(a, b, c) __builtin_amdgcn_mfma_f32_16x16x16bf16_1k(a, b, c, 0, 0, 0)

__device__ __forceinline__ void gload16(const bf16_t* g, bf16_t* l) {
  __builtin_amdgcn_global_load_lds(
      (__attribute__((address_space(1))) void*)g,
      (__attribute__((address_space(3))) void*)l, 16, 0, 0);
}

// ---------------------------------------------------------------- converts --
// One kernel, 1D grid 3648: blocks [0,3072) convert x fp32->bf16 (vectorized);
// blocks [3072,3648) transpose+convert the 4 weight matrices (64x64 LDS tiles).
__global__ __launch_bounds__(256) void cvt_all_kernel(
    const float* __restrict__ x, const float* __restrict__ W0,
    const float* __restrict__ W1, const float* __restrict__ W2,
    const float* __restrict__ W3, bf16_t* __restrict__ xb,
    bf16_t* __restrict__ T0, bf16_t* __restrict__ T1,
    bf16_t* __restrict__ T2, bf16_t* __restrict__ T3) {
  __shared__ bf16_t T[64][65];
  const int id = blockIdx.x;
  if (id < 3072) {
    int i = id * 256 + threadIdx.x;
    floatx4 v = ((const floatx4*)x)[i];
    bf16x4 o;
    o[0] = (bf16_t)v[0]; o[1] = (bf16_t)v[1]; o[2] = (bf16_t)v[2]; o[3] = (bf16_t)v[3];
    ((bf16x4*)xb)[i] = o;
    return;
  }
  const int wid = id - 3072;              // 0..575
  const int z = wid / 144, rem = wid % 144;
  const int by = rem / 12, bx = rem % 12;
  const float* W = (z == 0) ? W0 : (z == 1) ? W1 : (z == 2) ? W2 : W3;
  bf16_t* WT = (z == 0) ? T0 : (z == 1) ? T1 : (z == 2) ? T2 : T3;
  const int c = threadIdx.x & 63, r0 = threadIdx.x >> 6;
  const int i0 = by * 64, o0 = bx * 64;
#pragma unroll
  for (int p = 0; p < 16; ++p) {
    int r = p * 4 + r0;
    T[r][c] = (bf16_t)W[(i0 + r) * 768 + o0 + c];
  }
  __syncthreads();
#pragma unroll
  for (int p = 0; p < 16; ++p) {
    int r = p * 4 + r0;
    WT[(o0 + r) * 768 + i0 + c] = T[c][r];
  }
}

// ------------------------------------------------------------------- GEMMs --
#define LDPG 72  // BK=64 + 8 pad

// Fragment-order layouts (per bh = b*12+h, per 128-key tile kt):
//  K: elem(key,d) -> kt*8192 + ((nk*2+kk)*64 + quad*16 + l15)*8 + j
//     nk=key128>>4, l15=key128&15, kk=d>>5, quad=(d>>3)&3, j=d&7
//  V: elem(key,d) -> kt*8192 + ((nk*4+nd)*64 + vq*16 + vl15)*4 + j
//     nk=key128>>4, vq=(key128>>2)&3, j=key128&3, nd=d>>4, vl15=d&15

// Two-phase MLP staging: 8 independent loads in flight, then 8 ds_writes.
// Rows covered per thread: r0+{0,32,64,96} of the 128-row tile (same as R13's
// p-loop with c=p*256+tid), fixed 16B column q0c.
#define STAGE_MLP(GA, GB, KT)                              \
  bf16x8 a0 = *(const bf16x8*)((GA) + (KT));               \
  bf16x8 a1 = *(const bf16x8*)((GA) + (KT) + 32 * 768);    \
  bf16x8 a2 = *(const bf16x8*)((GA) + (KT) + 64 * 768);    \
  bf16x8 a3 = *(const bf16x8*)((GA) + (KT) + 96 * 768);    \
  bf16x8 b0 = *(const bf16x8*)((GB) + (KT));               \
  bf16x8 b1 = *(const bf16x8*)((GB) + (KT) + 32 * 768);    \
  bf16x8 b2 = *(const bf16x8*)((GB) + (KT) + 64 * 768);    \
  bf16x8 b3 = *(const bf16x8*)((GB) + (KT) + 96 * 768);    \
  *(bf16x8*)(lA) = a0;                                     \
  *(bf16x8*)(lA + 32 * LDPG) = a1;                         \
  *(bf16x8*)(lA + 64 * LDPG) = a2;                         \
  *(bf16x8*)(lA + 96 * LDPG) = a3;                         \
  *(bf16x8*)(lB) = b0;                                     \
  *(bf16x8*)(lB + 32 * LDPG) = b1;                         \
  *(bf16x8*)(lB + 64 * LDPG) = b2;                         \
  *(bf16x8*)(lB + 96 * LDPG) = b3;

// Fused QKV, M = output channels (768), N = tokens (4096).  Grid (32,6,3).
__global__ __launch_bounds__(256, 2) void gemm_qkv(
    const bf16_t* __restrict__ Xb, const bf16_t* __restrict__ WqT,
    const bf16_t* __restrict__ WkT, const bf16_t* __restrict__ WvT,
    const float* __restrict__ bq, const float* __restrict__ bk,
    const float* __restrict__ bv, bf16_t* __restrict__ qw,
    bf16_t* __restrict__ kw, bf16_t* __restrict__ vtw) {
  __shared__ bf16_t Al[128 * LDPG];
  __shared__ bf16_t Bl[128 * LDPG];
  const int z = blockIdx.z;
  const bf16_t* Wt = (z == 0) ? WqT : (z == 1) ? WkT : WvT;
  const float* bias = (z == 0) ? bq : (z == 1) ? bk : bv;
  const float oscale = (z == 0) ? 0.18033688011112042f : 1.0f;  // 0.125*log2(e)

  const int tid = threadIdx.x, lane = tid & 63, w = tid >> 6;
  const int wr = w >> 1, wc = w & 1;
  const int l15 = lane & 15, quad = lane >> 4;
  const int m0 = blockIdx.y * 128, n0 = blockIdx.x * 128;

  const int r0 = tid >> 3, q0c = (tid & 7) * 8;
  const bf16_t* gA = &Wt[(m0 + r0) * 768 + q0c];
  const bf16_t* gB = &Xb[(n0 + r0) * 768 + q0c];
  bf16_t* lA = &Al[r0 * LDPG + q0c];
  bf16_t* lB = &Bl[r0 * LDPG + q0c];

  floatx4 acc[4][4] = {};

  for (int kt = 0; kt < 768; kt += 64) {
    {
      STAGE_MLP(gA, gB, kt);
    }
    __syncthreads();
#pragma unroll
    for (int kk = 0; kk < 2; ++kk) {
      bf16x8 af[4], bfr[4];
#pragma unroll
      for (int i = 0; i < 4; ++i) {
        af[i]  = *(bf16x8*)&Al[(wr * 64 + i * 16 + l15) * LDPG + kk * 32 + quad * 8];
        bfr[i] = *(bf16x8*)&Bl[(wc * 64 + i * 16 + l15) * LDPG + kk * 32 + quad * 8];
      }
#pragma unroll
      for (int mi = 0; mi < 4; ++mi)
#pragma unroll
        for (int ni = 0; ni < 4; ++ni)
          acc[mi][ni] = MFMA32(af[mi], bfr[ni], acc[mi][ni]);
    }
    __syncthreads();
  }

  const int hh = (m0 + wr * 64) >> 6;  // head (64-aligned per wave-row)
#pragma unroll
  for (int mi = 0; mi < 4; ++mi) {
    const int d0 = mi * 16 + quad * 4;           // d within head, multiple of 4
    const int gm0 = m0 + wr * 64 + d0;
    float bv4[4];
#pragma unroll
    for (int r = 0; r < 4; ++r) bv4[r] = bias[gm0 + r];
#pragma unroll
    for (int ni = 0; ni < 4; ++ni) {
      const int gn = n0 + wc * 64 + ni * 16 + l15;
      const int bb = gn >> 11, tok = gn & 2047;
      const int bh = bb * 12 + hh;
      if (z == 0) {
        bf16x4 pk;
#pragma unroll
        for (int r = 0; r < 4; ++r)
          pk[r] = (bf16_t)((acc[mi][ni][r] + bv4[r]) * oscale);
        *(bf16x4*)&qw[bh * 131072 + tok * 64 + d0] = pk;
      } else if (z == 1) {
        const int kt2 = tok >> 7, k128 = tok & 127;
        const int nk = k128 >> 4, kl15 = k128 & 15;
        const int kk = d0 >> 5, kq = (d0 >> 3) & 3, j0 = d0 & 7;
        bf16x4 pk;
#pragma unroll
        for (int r = 0; r < 4; ++r)
          pk[r] = (bf16_t)(acc[mi][ni][r] + bv4[r]);
        *(bf16x4*)&kw[bh * 131072 + kt2 * 8192 +
                      ((nk * 2 + kk) * 64 + kq * 16 + kl15) * 8 + j0] = pk;
      } else {
        const int kt2 = tok >> 7, k128 = tok & 127;
        const int nk = k128 >> 4, vq = (k128 >> 2) & 3, j = k128 & 3;
        const int nd = d0 >> 4, vl0 = d0 & 15;
        const int base = bh * 131072 + kt2 * 8192 +
                         ((nk * 4 + nd) * 64 + vq * 16 + vl0) * 4 + j;
#pragma unroll
        for (int r = 0; r < 4; ++r)
          vtw[base + r * 4] = (bf16_t)(acc[mi][ni][r] + bv4[r]);
      }
    }
  }
}

// Output projection, M = channels: out fp32 [4096 tok][768 ch].  Grid (32,6).
__global__ __launch_bounds__(256, 2) void gemm_proj(
    const bf16_t* __restrict__ Yb, const bf16_t* __restrict__ WpT,
    const float* __restrict__ bias, float* __restrict__ out) {
  __shared__ bf16_t Al[128 * LDPG];
  __shared__ bf16_t Bl[128 * LDPG];
  const int tid = threadIdx.x, lane = tid & 63, w = tid >> 6;
  const int wr = w >> 1, wc = w & 1;
  const int l15 = lane & 15, quad = lane >> 4;
  const int m0 = blockIdx.y * 128, n0 = blockIdx.x * 128;

  const int r0 = tid >> 3, q0c = (tid & 7) * 8;
  const bf16_t* gA = &WpT[(m0 + r0) * 768 + q0c];
  const bf16_t* gB = &Yb[(n0 + r0) * 768 + q0c];
  bf16_t* lA = &Al[r0 * LDPG + q0c];
  bf16_t* lB = &Bl[r0 * LDPG + q0c];

  floatx4 acc[4][4] = {};

  for (int kt = 0; kt < 768; kt += 64) {
    {
      STAGE_MLP(gA, gB, kt);
    }
    __syncthreads();
#pragma unroll
    for (int kk = 0; kk < 2; ++kk) {
      bf16x8 af[4], bfr[4];
#pragma unroll
      for (int i = 0; i < 4; ++i) {
        af[i]  = *(bf16x8*)&Al[(wr * 64 + i * 16 + l15) * LDPG + kk * 32 + quad * 8];
        bfr[i] = *(bf16x8*)&Bl[(wc * 64 + i * 16 + l15) * LDPG + kk * 32 + quad * 8];
      }
#pragma unroll
      for (int mi = 0; mi < 4; ++mi)
#pragma unroll
        for (int ni = 0; ni < 4; ++ni)
          acc[mi][ni] = MFMA32(af[mi], bfr[ni], acc[mi][ni]);
    }
    __syncthreads();
  }

#pragma unroll
  for (int mi = 0; mi < 4; ++mi) {
    const int gm0 = m0 + wr * 64 + mi * 16 + quad * 4;
    floatx4 bv4;
#pragma unroll
    for (int r = 0; r < 4; ++r) bv4[r] = bias[gm0 + r];
#pragma unroll
    for (int ni = 0; ni < 4; ++ni) {
      const int gn = n0 + wc * 64 + ni * 16 + l15;
      floatx4 v = acc[mi][ni] + bv4;
      *(floatx4*)&out[gn * 768 + gm0] = v;
    }
  }
}

// --------------------------------------------------------------- attention --
// Block: one (b,h), 64 Q rows.  Wave w=(wk<<1)|wq: wq picks 32-q half, wk picks
// the 32-key half of each 64-key tile.  K/V in fragment order -> each 64-key
// subtile is a contiguous 8KB range; staging = linear global_load_lds copy
// (no VGPRs, no VALU).  Double-buffered: stage(next) overlaps compute(cur);
// one __syncthreads per tile (its vmcnt(0) drain hits loads issued a full
// compute-phase earlier).  XCD mapping: block i -> XCD i&7; XCD x owns bh in
// [3x,3x+3) (1.5MB K/V, L2-resident).  lsum on MFMA pipe (ones-trick).
__global__ __launch_bounds__(256, 4) void attn_kernel(
    const bf16_t* __restrict__ Q, const bf16_t* __restrict__ Kf,
    const bf16_t* __restrict__ Vf, bf16_t* __restrict__ Y) {
  // buf b at smem+b*8192: K [0,4096), V [4096,8192) (elements)
  __shared__ __align__(16) bf16_t smem[16384];
  __shared__ float Ls[2][2][2][16];             // [wq][wk][ni][q&15]
  float* Ox = (float*)smem;                     // exchange region (16 KB used)

  const int tid = threadIdx.x, lane = tid & 63, w = tid >> 6;
  const int wq = w & 1, wk = w >> 1;
  const int l15 = lane & 15, quad = lane >> 4;

  // XCD-aware mapping (perf-only heuristic; any mapping is correct).
  const int i = blockIdx.x;           // 0..767
  const int xcd = i & 7, j = i >> 3;  // j: 0..95
  const int bh = xcd * 3 + (j >> 5);
  const int q0 = (j & 31) * 64;

  const bf16_t* Qb = Q + bh * 131072;
  const bf16_t* Kg = Kf + bh * 131072 + tid * 8;  // per-thread staging base
  const bf16_t* Vg = Vf + bh * 131072 + tid * 8;

  // Q B-frags (x32): n=q over l15, k=dh over quad*8+j.  32 q per wave.
  bf16x8 qf[2][2];
#pragma unroll
  for (int ni = 0; ni < 2; ++ni)
#pragma unroll
    for (int kk = 0; kk < 2; ++kk)
      qf[ni][kk] = *(const bf16x8*)&Qb[(q0 + wq * 32 + ni * 16 + l15) * 64 +
                                       kk * 32 + quad * 8];

  floatx4 oacc[2][4] = {};   // [ni(q16)][nd(d16)] partial over this wave's keys
  floatx4 sacc[2] = {};      // row-sums via MFMA ones-trick
  const short4_t ones = {0x3F80, 0x3F80, 0x3F80, 0x3F80};  // bf16 1.0 x4

  // stage 64-key tile t (elements [t*4096, t*4096+4096) of K and of V) into buf b
  auto stage = [&](int b, int t) {
    const bf16_t* kg = Kg + t * 4096;
    const bf16_t* vg = Vg + t * 4096;
    bf16_t* kl = smem + b * 8192 + tid * 8;
    bf16_t* vl = smem + b * 8192 + 4096 + tid * 8;
    gload16(kg, kl);
    gload16(kg + 2048, kl + 2048);
    gload16(vg, vl);
    gload16(vg + 2048, vl + 2048);
  };

  auto compute = [&](int b) {
    const bf16_t* Kl = smem + b * 8192;
    const bf16_t* Vl = smem + b * 8192 + 4096;
    // S^T = K*Q^T for this wave's 32 keys x 32 q; P = exp2 packed to x16 A-frags.
    short4_t pk[2][2];
#pragma unroll
    for (int mt = 0; mt < 2; ++mt) {
      floatx4 s[2] = {};
#pragma unroll
      for (int kk = 0; kk < 2; ++kk) {
        bf16x8 kfr = *(const bf16x8*)&Kl[((wk * 2 + mt) * 2 + kk) * 512 + lane * 8];
#pragma unroll
        for (int ni = 0; ni < 2; ++ni)
          s[ni] = MFMA32(kfr, qf[ni][kk], s[ni]);
      }
#pragma unroll
      for (int ni = 0; ni < 2; ++ni) {
        bf16x4 ph;
#pragma unroll
        for (int r = 0; r < 4; ++r)
          ph[r] = (bf16_t)__builtin_amdgcn_exp2f(s[ni][r]);
        pk[mt][ni] = __builtin_bit_cast(short4_t, ph);
      }
    }
    // O += P*V; sacc += P*1 (row-sums on the MFMA pipe).
#pragma unroll
    for (int mt = 0; mt < 2; ++mt) {
#pragma unroll
      for (int nd = 0; nd < 4; ++nd) {
        bf16x4 vfr = *(const bf16x4*)&Vl[((wk * 2 + mt) * 4 + nd) * 256 + lane * 4];
        short4_t vs = __builtin_bit_cast(short4_t, vfr);
#pragma unroll
        for (int ni = 0; ni < 2; ++ni)
          oacc[ni][nd] = MFMA16(pk[mt][ni], vs, oacc[ni][nd]);
      }
#pragma unroll
      for (int ni = 0; ni < 2; ++ni)
        sacc[ni] = MFMA16(pk[mt][ni], ones, sacc[ni]);
    }
  };

  stage(0, 0);
  __syncthreads();                       // buf0 ready (vmcnt(0) drain + barrier)
  for (int t = 0; t < 32; t += 2) {
    stage(1, t + 1);                     // async into buf1 during compute(buf0)
    compute(0);
    __syncthreads();                     // buf1 ready; everyone done with buf0
    if (t + 2 < 32) stage(0, t + 2);     // async into buf0 during compute(buf1)
    compute(1);
    __syncthreads();                     // buf0 ready; everyone done with buf1
  }

  // sacc[ni][r] = this wave's lsum for q = ni*16 + quad*4 + r (same across l15).
  if (l15 == 0) {
#pragma unroll
    for (int ni = 0; ni < 2; ++ni)
#pragma unroll
      for (int r = 0; r < 4; ++r)
        Ls[wq][wk][ni][quad * 4 + r] = sacc[ni][r];
  }

  // Each wave writes its NON-owned d-half (fp32, b128, conflict-free),
  // then reads partner's partial for its owned half.
#pragma unroll
  for (int ni = 0; ni < 2; ++ni)
#pragma unroll
    for (int ndl = 0; ndl < 2; ++ndl) {
      const int nd = (1 - wk) * 2 + ndl;
      *(floatx4*)&Ox[((((wq * 2 + wk) * 2 + ni) * 2 + ndl) * 64 + lane) * 4] =
          oacc[ni][nd];
    }
  __syncthreads();

  const int bb = bh / 12, h = bh % 12;
#pragma unroll
  for (int ni = 0; ni < 2; ++ni) {
    float tot[4];
#pragma unroll
    for (int r = 0; r < 4; ++r)
      tot[r] = Ls[wq][0][ni][quad * 4 + r] + Ls[wq][1][ni][quad * 4 + r];
#pragma unroll
    for (int ndl = 0; ndl < 2; ++ndl) {
      const int nd = wk * 2 + ndl;
      floatx4 o = oacc[ni][nd];
      floatx4 other =
          *(floatx4*)&Ox[((((wq * 2 + (1 - wk)) * 2 + ni) * 2 + ndl) * 64 + lane) * 4];
      o += other;
#pragma unroll
      for (int r = 0; r < 4; ++r) {
        const int tok = q0 + wq * 32 + ni * 16 + quad * 4 + r;
        const int col = h * 64 + nd * 16 + l15;
        Y[(bb * 2048 + tok) * 768 + col] = (bf16_t)(o[r] / tot[r]);
      }
    }
  }
}

// ------------------------------------------------------------------ launch --
extern "C" void kernel_launch(void* const* d_in, const int* in_sizes, int n_in,
                              void* d_out, int out_size, void* d_ws, size_t ws_size,
                              hipStream_t stream) {
  const float* x  = (const float*)d_in[0];
  const float* Wq = (const float*)d_in[1];
  const float* bq = (const float*)d_in[2];
  const float* Wk = (const float*)d_in[3];
  const float* bk = (const float*)d_in[4];
  const float* Wv = (const float*)d_in[5];
  const float* bv = (const float*)d_in[6];
  const float* Wp = (const float*)d_in[7];
  const float* bp = (const float*)d_in[8];
  float* out = (float*)d_out;

  char* ws = (char*)d_ws;
  bf16_t* xb  = (bf16_t*)ws; ws += (size_t)4096 * 768 * 2;
  bf16_t* WqT = (bf16_t*)ws; ws += (size_t)768 * 768 * 2;
  bf16_t* WkT = (bf16_t*)ws; ws += (size_t)768 * 768 * 2;
  bf16_t* WvT = (bf16_t*)ws; ws += (size_t)768 * 768 * 2;
  bf16_t* WpT = (bf16_t*)ws; ws += (size_t)768 * 768 * 2;
  bf16_t* qw  = (bf16_t*)ws; ws += (size_t)24 * 2048 * 64 * 2;
  bf16_t* kw  = (bf16_t*)ws; ws += (size_t)24 * 2048 * 64 * 2;
  bf16_t* vtw = (bf16_t*)ws; ws += (size_t)24 * 2048 * 64 * 2;
  bf16_t* yw  = (bf16_t*)ws; ws += (size_t)4096 * 768 * 2;

  cvt_all_kernel<<<3648, 256, 0, stream>>>(x, Wq, Wk, Wv, Wp, xb, WqT, WkT, WvT, WpT);
  gemm_qkv<<<dim3(32, 6, 3), 256, 0, stream>>>(xb, WqT, WkT, WvT, bq, bk, bv, qw, kw, vtw);
  attn_kernel<<<768, 256, 0, stream>>>(qw, kw, vtw, yw);
  gemm_proj<<<dim3(32, 6), 256, 0, stream>>>(yw, WpT, bp, out);
}

// Round 11
// 173.830 us; speedup vs baseline: 1.1577x; 1.0221x over previous
//
#include <hip/hip_runtime.h>

// MultiHeadAttention: B=2, N=2048, C=768, H=12, DH=64. fp32 in/out, bf16 MFMA compute.
// R16 = R15 (177.7us best) + T14 issue-early/write-late in both GEMMs:
//  - two NAMED register sets (pa*/qa*); tile kt+1's 8 loads issued BEFORE
//    compute(kt); ds_writes happen after the post-compute barrier -> L2 latency
//    (~200-400cy) hides under the ~400cy MFMA phase instead of stalling the
//    stage.  Same addresses, same barrier count, same MFMA order -> numerics
//    bit-identical.  launch_bounds(256,2) keeps the 256-VGPR budget (R15-proven).
// attn / cvt_all byte-identical to R15.

typedef __bf16 bf16_t;
typedef __bf16 bf16x8 __attribute__((ext_vector_type(8)));
typedef __bf16 bf16x4 __attribute__((ext_vector_type(4)));
typedef short  short4_t __attribute__((ext_vector_type(4)));
typedef float  floatx4 __attribute__((ext_vector_type(4)));

#define MFMA32(a, b, c) __builtin_amdgcn_mfma_f32_16x16x32_bf16(a, b, c, 0, 0, 0)
#define MFMA16(a, b, c) __builtin_amdgcn_mfma_f32_16x16x16bf16_1k(a, b, c, 0, 0, 0)

__device__ __forceinline__ void gload16(const bf16_t* g, bf16_t* l) {
  __builtin_amdgcn_global_load_lds(
      (__attribute__((address_space(1))) void*)g,
      (__attribute__((address_space(3))) void*)l, 16, 0, 0);
}

// ---------------------------------------------------------------- converts --
// One kernel, 1D grid 3648: blocks [0,3072) convert x fp32->bf16 (vectorized);
// blocks [3072,3648) transpose+convert the 4 weight matrices (64x64 LDS tiles).
__global__ __launch_bounds__(256) void cvt_all_kernel(
    const float* __restrict__ x, const float* __restrict__ W0,
    const float* __restrict__ W1, const float* __restrict__ W2,
    const float* __restrict__ W3, bf16_t* __restrict__ xb,
    bf16_t* __restrict__ T0, bf16_t* __restrict__ T1,
    bf16_t* __restrict__ T2, bf16_t* __restrict__ T3) {
  __shared__ bf16_t T[64][65];
  const int id = blockIdx.x;
  if (id < 3072) {
    int i = id * 256 + threadIdx.x;
    floatx4 v = ((const floatx4*)x)[i];
    bf16x4 o;
    o[0] = (bf16_t)v[0]; o[1] = (bf16_t)v[1]; o[2] = (bf16_t)v[2]; o[3] = (bf16_t)v[3];
    ((bf16x4*)xb)[i] = o;
    return;
  }
  const int wid = id - 3072;              // 0..575
  const int z = wid / 144, rem = wid % 144;
  const int by = rem / 12, bx = rem % 12;
  const float* W = (z == 0) ? W0 : (z == 1) ? W1 : (z == 2) ? W2 : W3;
  bf16_t* WT = (z == 0) ? T0 : (z == 1) ? T1 : (z == 2) ? T2 : T3;
  const int c = threadIdx.x & 63, r0 = threadIdx.x >> 6;
  const int i0 = by * 64, o0 = bx * 64;
#pragma unroll
  for (int p = 0; p < 16; ++p) {
    int r = p * 4 + r0;
    T[r][c] = (bf16_t)W[(i0 + r) * 768 + o0 + c];
  }
  __syncthreads();
#pragma unroll
  for (int p = 0; p < 16; ++p) {
    int r = p * 4 + r0;
    WT[(o0 + r) * 768 + i0 + c] = T[c][r];
  }
}

// ------------------------------------------------------------------- GEMMs --
#define LDPG 72  // BK=64 + 8 pad

// Fragment-order layouts (per bh = b*12+h, per 128-key tile kt):
//  K: elem(key,d) -> kt*8192 + ((nk*2+kk)*64 + quad*16 + l15)*8 + j
//     nk=key128>>4, l15=key128&15, kk=d>>5, quad=(d>>3)&3, j=d&7
//  V: elem(key,d) -> kt*8192 + ((nk*4+nd)*64 + vq*16 + vl15)*4 + j
//     nk=key128>>4, vq=(key128>>2)&3, j=key128&3, nd=d>>4, vl15=d&15

// T14 staging: LOADSET issues 8 independent global loads into NAMED regs;
// WRITESET commits them to LDS (after the barrier, a compute-phase later).
#define LOADSET(A0, A1, A2, A3, B0, B1, B2, B3, KT)        \
  A0 = *(const bf16x8*)(gA + (KT));                        \
  A1 = *(const bf16x8*)(gA + (KT) + 32 * 768);             \
  A2 = *(const bf16x8*)(gA + (KT) + 64 * 768);             \
  A3 = *(const bf16x8*)(gA + (KT) + 96 * 768);             \
  B0 = *(const bf16x8*)(gB + (KT));                        \
  B1 = *(const bf16x8*)(gB + (KT) + 32 * 768);             \
  B2 = *(const bf16x8*)(gB + (KT) + 64 * 768);             \
  B3 = *(const bf16x8*)(gB + (KT) + 96 * 768);

#define WRITESET(A0, A1, A2, A3, B0, B1, B2, B3)           \
  *(bf16x8*)(lA) = A0;                                     \
  *(bf16x8*)(lA + 32 * LDPG) = A1;                         \
  *(bf16x8*)(lA + 64 * LDPG) = A2;                         \
  *(bf16x8*)(lA + 96 * LDPG) = A3;                         \
  *(bf16x8*)(lB) = B0;                                     \
  *(bf16x8*)(lB + 32 * LDPG) = B1;                         \
  *(bf16x8*)(lB + 64 * LDPG) = B2;                         \
  *(bf16x8*)(lB + 96 * LDPG) = B3;

#define GCOMPUTE()                                                          \
  {                                                                         \
    bf16x8 af[4], bfr[4];                                                   \
    _Pragma("unroll") for (int i = 0; i < 4; ++i) {                         \
      af[i]  = *(bf16x8*)&Al[(wr * 64 + i * 16 + l15) * LDPG + kk2 * 32 + quad * 8]; \
      bfr[i] = *(bf16x8*)&Bl[(wc * 64 + i * 16 + l15) * LDPG + kk2 * 32 + quad * 8]; \
    }                                                                       \
    _Pragma("unroll") for (int mi = 0; mi < 4; ++mi)                        \
        _Pragma("unroll") for (int ni = 0; ni < 4; ++ni)                    \
            acc[mi][ni] = MFMA32(af[mi], bfr[ni], acc[mi][ni]);             \
  }

#define GCOMPUTE2()                                \
  _Pragma("unroll") for (int kk2 = 0; kk2 < 2; ++kk2) GCOMPUTE()

// Fused QKV, M = output channels (768), N = tokens (4096).  Grid (32,6,3).
__global__ __launch_bounds__(256, 2) void gemm_qkv(
    const bf16_t* __restrict__ Xb, const bf16_t* __restrict__ WqT,
    const bf16_t* __restrict__ WkT, const bf16_t* __restrict__ WvT,
    const float* __restrict__ bq, const float* __restrict__ bk,
    const float* __restrict__ bv, bf16_t* __restrict__ qw,
    bf16_t* __restrict__ kw, bf16_t* __restrict__ vtw) {
  __shared__ bf16_t Al[128 * LDPG];
  __shared__ bf16_t Bl[128 * LDPG];
  const int z = blockIdx.z;
  const bf16_t* Wt = (z == 0) ? WqT : (z == 1) ? WkT : WvT;
  const float* bias = (z == 0) ? bq : (z == 1) ? bk : bv;
  const float oscale = (z == 0) ? 0.18033688011112042f : 1.0f;  // 0.125*log2(e)

  const int tid = threadIdx.x, lane = tid & 63, w = tid >> 6;
  const int wr = w >> 1, wc = w & 1;
  const int l15 = lane & 15, quad = lane >> 4;
  const int m0 = blockIdx.y * 128, n0 = blockIdx.x * 128;

  const int r0 = tid >> 3, q0c = (tid & 7) * 8;
  const bf16_t* gA = &Wt[(m0 + r0) * 768 + q0c];
  const bf16_t* gB = &Xb[(n0 + r0) * 768 + q0c];
  bf16_t* lA = &Al[r0 * LDPG + q0c];
  bf16_t* lB = &Bl[r0 * LDPG + q0c];

  floatx4 acc[4][4] = {};
  bf16x8 pa0, pa1, pa2, pa3, pb0, pb1, pb2, pb3;   // even-tile staging regs
  bf16x8 qa0, qa1, qa2, qa3, qb0, qb1, qb2, qb3;   // odd-tile staging regs

  LOADSET(pa0, pa1, pa2, pa3, pb0, pb1, pb2, pb3, 0);
  for (int kt = 0; kt < 768; kt += 128) {
    WRITESET(pa0, pa1, pa2, pa3, pb0, pb1, pb2, pb3);
    __syncthreads();
    LOADSET(qa0, qa1, qa2, qa3, qb0, qb1, qb2, qb3, kt + 64);
    GCOMPUTE2();
    __syncthreads();
    WRITESET(qa0, qa1, qa2, qa3, qb0, qb1, qb2, qb3);
    __syncthreads();
    if (kt + 128 < 768) LOADSET(pa0, pa1, pa2, pa3, pb0, pb1, pb2, pb3, kt + 128);
    GCOMPUTE2();
    __syncthreads();
  }

  const int hh = (m0 + wr * 64) >> 6;  // head (64-aligned per wave-row)
#pragma unroll
  for (int mi = 0; mi < 4; ++mi) {
    const int d0 = mi * 16 + quad * 4;           // d within head, multiple of 4
    const int gm0 = m0 + wr * 64 + d0;
    float bv4[4];
#pragma unroll
    for (int r = 0; r < 4; ++r) bv4[r] = bias[gm0 + r];
#pragma unroll
    for (int ni = 0; ni < 4; ++ni) {
      const int gn = n0 + wc * 64 + ni * 16 + l15;
      const int bb = gn >> 11, tok = gn & 2047;
      const int bh = bb * 12 + hh;
      if (z == 0) {
        bf16x4 pk;
#pragma unroll
        for (int r = 0; r < 4; ++r)
          pk[r] = (bf16_t)((acc[mi][ni][r] + bv4[r]) * oscale);
        *(bf16x4*)&qw[bh * 131072 + tok * 64 + d0] = pk;
      } else if (z == 1) {
        const int kt2 = tok >> 7, k128 = tok & 127;
        const int nk = k128 >> 4, kl15 = k128 & 15;
        const int kk = d0 >> 5, kq = (d0 >> 3) & 3, j0 = d0 & 7;
        bf16x4 pk;
#pragma unroll
        for (int r = 0; r < 4; ++r)
          pk[r] = (bf16_t)(acc[mi][ni][r] + bv4[r]);
        *(bf16x4*)&kw[bh * 131072 + kt2 * 8192 +
                      ((nk * 2 + kk) * 64 + kq * 16 + kl15) * 8 + j0] = pk;
      } else {
        const int kt2 = tok >> 7, k128 = tok & 127;
        const int nk = k128 >> 4, vq = (k128 >> 2) & 3, j = k128 & 3;
        const int nd = d0 >> 4, vl0 = d0 & 15;
        const int base = bh * 131072 + kt2 * 8192 +
                         ((nk * 4 + nd) * 64 + vq * 16 + vl0) * 4 + j;
#pragma unroll
        for (int r = 0; r < 4; ++r)
          vtw[base + r * 4] = (bf16_t)(acc[mi][ni][r] + bv4[r]);
      }
    }
  }
}

// Output projection, M = channels: out fp32 [4096 tok][768 ch].  Grid (32,6).
__global__ __launch_bounds__(256, 2) void gemm_proj(
    const bf16_t* __restrict__ Yb, const bf16_t* __restrict__ WpT,
    const float* __restrict__ bias, float* __restrict__ out) {
  __shared__ bf16_t Al[128 * LDPG];
  __shared__ bf16_t Bl[128 * LDPG];
  const int tid = threadIdx.x, lane = tid & 63, w = tid >> 6;
  const int wr = w >> 1, wc = w & 1;
  const int l15 = lane & 15, quad = lane >> 4;
  const int m0 = blockIdx.y * 128, n0 = blockIdx.x * 128;

  const int r0 = tid >> 3, q0c = (tid & 7) * 8;
  const bf16_t* gA = &WpT[(m0 + r0) * 768 + q0c];
  const bf16_t* gB = &Yb[(n0 + r0) * 768 + q0c];
  bf16_t* lA = &Al[r0 * LDPG + q0c];
  bf16_t* lB = &Bl[r0 * LDPG + q0c];

  floatx4 acc[4][4] = {};
  bf16x8 pa0, pa1, pa2, pa3, pb0, pb1, pb2, pb3;
  bf16x8 qa0, qa1, qa2, qa3, qb0, qb1, qb2, qb3;

  LOADSET(pa0, pa1, pa2, pa3, pb0, pb1, pb2, pb3, 0);
  for (int kt = 0; kt < 768; kt += 128) {
    WRITESET(pa0, pa1, pa2, pa3, pb0, pb1, pb2, pb3);
    __syncthreads();
    LOADSET(qa0, qa1, qa2, qa3, qb0, qb1, qb2, qb3, kt + 64);
    GCOMPUTE2();
    __syncthreads();
    WRITESET(qa0, qa1, qa2, qa3, qb0, qb1, qb2, qb3);
    __syncthreads();
    if (kt + 128 < 768) LOADSET(pa0, pa1, pa2, pa3, pb0, pb1, pb2, pb3, kt + 128);
    GCOMPUTE2();
    __syncthreads();
  }

#pragma unroll
  for (int mi = 0; mi < 4; ++mi) {
    const int gm0 = m0 + wr * 64 + mi * 16 + quad * 4;
    floatx4 bv4;
#pragma unroll
    for (int r = 0; r < 4; ++r) bv4[r] = bias[gm0 + r];
#pragma unroll
    for (int ni = 0; ni < 4; ++ni) {
      const int gn = n0 + wc * 64 + ni * 16 + l15;
      floatx4 v = acc[mi][ni] + bv4;
      *(floatx4*)&out[gn * 768 + gm0] = v;
    }
  }
}

// --------------------------------------------------------------- attention --
// Block: one (b,h), 64 Q rows.  Wave w=(wk<<1)|wq: wq picks 32-q half, wk picks
// the 32-key half of each 64-key tile.  K/V in fragment order -> each 64-key
// subtile is a contiguous 8KB range; staging = linear global_load_lds copy
// (no VGPRs, no VALU).  Double-buffered: stage(next) overlaps compute(cur);
// one __syncthreads per tile (its vmcnt(0) drain hits loads issued a full
// compute-phase earlier).  XCD mapping: block i -> XCD i&7; XCD x owns bh in
// [3x,3x+3) (1.5MB K/V, L2-resident).  lsum on MFMA pipe (ones-trick).
__global__ __launch_bounds__(256, 4) void attn_kernel(
    const bf16_t* __restrict__ Q, const bf16_t* __restrict__ Kf,
    const bf16_t* __restrict__ Vf, bf16_t* __restrict__ Y) {
  // buf b at smem+b*8192: K [0,4096), V [4096,8192) (elements)
  __shared__ __align__(16) bf16_t smem[16384];
  __shared__ float Ls[2][2][2][16];             // [wq][wk][ni][q&15]
  float* Ox = (float*)smem;                     // exchange region (16 KB used)

  const int tid = threadIdx.x, lane = tid & 63, w = tid >> 6;
  const int wq = w & 1, wk = w >> 1;
  const int l15 = lane & 15, quad = lane >> 4;

  // XCD-aware mapping (perf-only heuristic; any mapping is correct).
  const int i = blockIdx.x;           // 0..767
  const int xcd = i & 7, j = i >> 3;  // j: 0..95
  const int bh = xcd * 3 + (j >> 5);
  const int q0 = (j & 31) * 64;

  const bf16_t* Qb = Q + bh * 131072;
  const bf16_t* Kg = Kf + bh * 131072 + tid * 8;  // per-thread staging base
  const bf16_t* Vg = Vf + bh * 131072 + tid * 8;

  // Q B-frags (x32): n=q over l15, k=dh over quad*8+j.  32 q per wave.
  bf16x8 qf[2][2];
#pragma unroll
  for (int ni = 0; ni < 2; ++ni)
#pragma unroll
    for (int kk = 0; kk < 2; ++kk)
      qf[ni][kk] = *(const bf16x8*)&Qb[(q0 + wq * 32 + ni * 16 + l15) * 64 +
                                       kk * 32 + quad * 8];

  floatx4 oacc[2][4] = {};   // [ni(q16)][nd(d16)] partial over this wave's keys
  floatx4 sacc[2] = {};      // row-sums via MFMA ones-trick
  const short4_t ones = {0x3F80, 0x3F80, 0x3F80, 0x3F80};  // bf16 1.0 x4

  // stage 64-key tile t (elements [t*4096, t*4096+4096) of K and of V) into buf b
  auto stage = [&](int b, int t) {
    const bf16_t* kg = Kg + t * 4096;
    const bf16_t* vg = Vg + t * 4096;
    bf16_t* kl = smem + b * 8192 + tid * 8;
    bf16_t* vl = smem + b * 8192 + 4096 + tid * 8;
    gload16(kg, kl);
    gload16(kg + 2048, kl + 2048);
    gload16(vg, vl);
    gload16(vg + 2048, vl + 2048);
  };

  auto compute = [&](int b) {
    const bf16_t* Kl = smem + b * 8192;
    const bf16_t* Vl = smem + b * 8192 + 4096;
    // S^T = K*Q^T for this wave's 32 keys x 32 q; P = exp2 packed to x16 A-frags.
    short4_t pk[2][2];
#pragma unroll
    for (int mt = 0; mt < 2; ++mt) {
      floatx4 s[2] = {};
#pragma unroll
      for (int kk = 0; kk < 2; ++kk) {
        bf16x8 kfr = *(const bf16x8*)&Kl[((wk * 2 + mt) * 2 + kk) * 512 + lane * 8];
#pragma unroll
        for (int ni = 0; ni < 2; ++ni)
          s[ni] = MFMA32(kfr, qf[ni][kk], s[ni]);
      }
#pragma unroll
      for (int ni = 0; ni < 2; ++ni) {
        bf16x4 ph;
#pragma unroll
        for (int r = 0; r < 4; ++r)
          ph[r] = (bf16_t)__builtin_amdgcn_exp2f(s[ni][r]);
        pk[mt][ni] = __builtin_bit_cast(short4_t, ph);
      }
    }
    // O += P*V; sacc += P*1 (row-sums on the MFMA pipe).
#pragma unroll
    for (int mt = 0; mt < 2; ++mt) {
#pragma unroll
      for (int nd = 0; nd < 4; ++nd) {
        bf16x4 vfr = *(const bf16x4*)&Vl[((wk * 2 + mt) * 4 + nd) * 256 + lane * 4];
        short4_t vs = __builtin_bit_cast(short4_t, vfr);
#pragma unroll
        for (int ni = 0; ni < 2; ++ni)
          oacc[ni][nd] = MFMA16(pk[mt][ni], vs, oacc[ni][nd]);
      }
#pragma unroll
      for (int ni = 0; ni < 2; ++ni)
        sacc[ni] = MFMA16(pk[mt][ni], ones, sacc[ni]);
    }
  };

  stage(0, 0);
  __syncthreads();                       // buf0 ready (vmcnt(0) drain + barrier)
  for (int t = 0; t < 32; t += 2) {
    stage(1, t + 1);                     // async into buf1 during compute(buf0)
    compute(0);
    __syncthreads();                     // buf1 ready; everyone done with buf0
    if (t + 2 < 32) stage(0, t + 2);     // async into buf0 during compute(buf1)
    compute(1);
    __syncthreads();                     // buf0 ready; everyone done with buf1
  }

  // sacc[ni][r] = this wave's lsum for q = ni*16 + quad*4 + r (same across l15).
  if (l15 == 0) {
#pragma unroll
    for (int ni = 0; ni < 2; ++ni)
#pragma unroll
      for (int r = 0; r < 4; ++r)
        Ls[wq][wk][ni][quad * 4 + r] = sacc[ni][r];
  }

  // Each wave writes its NON-owned d-half (fp32, b128, conflict-free),
  // then reads partner's partial for its owned half.
#pragma unroll
  for (int ni = 0; ni < 2; ++ni)
#pragma unroll
    for (int ndl = 0; ndl < 2; ++ndl) {
      const int nd = (1 - wk) * 2 + ndl;
      *(floatx4*)&Ox[((((wq * 2 + wk) * 2 + ni) * 2 + ndl) * 64 + lane) * 4] =
          oacc[ni][nd];
    }
  __syncthreads();

  const int bb = bh / 12, h = bh % 12;
#pragma unroll
  for (int ni = 0; ni < 2; ++ni) {
    float tot[4];
#pragma unroll
    for (int r = 0; r < 4; ++r)
      tot[r] = Ls[wq][0][ni][quad * 4 + r] + Ls[wq][1][ni][quad * 4 + r];
#pragma unroll
    for (int ndl = 0; ndl < 2; ++ndl) {
      const int nd = wk * 2 + ndl;
      floatx4 o = oacc[ni][nd];
      floatx4 other =
          *(floatx4*)&Ox[((((wq * 2 + (1 - wk)) * 2 + ni) * 2 + ndl) * 64 + lane) * 4];
      o += other;
#pragma unroll
      for (int r = 0; r < 4; ++r) {
        const int tok = q0 + wq * 32 + ni * 16 + quad * 4 + r;
        const int col = h * 64 + nd * 16 + l15;
        Y[(bb * 2048 + tok) * 768 + col] = (bf16_t)(o[r] / tot[r]);
      }
    }
  }
}

// ------------------------------------------------------------------ launch --
extern "C" void kernel_launch(void* const* d_in, const int* in_sizes, int n_in,
                              void* d_out, int out_size, void* d_ws, size_t ws_size,
                              hipStream_t stream) {
  const float* x  = (const float*)d_in[0];
  const float* Wq = (const float*)d_in[1];
  const float* bq = (const float*)d_in[2];
  const float* Wk = (const float*)d_in[3];
  const float* bk = (const float*)d_in[4];
  const float* Wv = (const float*)d_in[5];
  const float* bv = (const float*)d_in[6];
  const float* Wp = (const float*)d_in[7];
  const float* bp = (const float*)d_in[8];
  float* out = (float*)d_out;

  char* ws = (char*)d_ws;
  bf16_t* xb  = (bf16_t*)ws; ws += (size_t)4096 * 768 * 2;
  bf16_t* WqT = (bf16_t*)ws; ws += (size_t)768 * 768 * 2;
  bf16_t* WkT = (bf16_t*)ws; ws += (size_t)768 * 768 * 2;
  bf16_t* WvT = (bf16_t*)ws; ws += (size_t)768 * 768 * 2;
  bf16_t* WpT = (bf16_t*)ws; ws += (size_t)768 * 768 * 2;
  bf16_t* qw  = (bf16_t*)ws; ws += (size_t)24 * 2048 * 64 * 2;
  bf16_t* kw  = (bf16_t*)ws; ws += (size_t)24 * 2048 * 64 * 2;
  bf16_t* vtw = (bf16_t*)ws; ws += (size_t)24 * 2048 * 64 * 2;
  bf16_t* yw  = (bf16_t*)ws; ws += (size_t)4096 * 768 * 2;

  cvt_all_kernel<<<3648, 256, 0, stream>>>(x, Wq, Wk, Wv, Wp, xb, WqT, WkT, WvT, WpT);
  gemm_qkv<<<dim3(32, 6, 3), 256, 0, stream>>>(xb, WqT, WkT, WvT, bq, bk, bv, qw, kw, vtw);
  attn_kernel<<<768, 256, 0, stream>>>(qw, kw, vtw, yw);
  gemm_proj<<<dim3(32, 6), 256, 0, stream>>>(yw, WpT, bp, out);
}